// Round 1
// baseline (739.664 us; speedup 1.0000x reference)
//
#include <hip/hip_runtime.h>

typedef _Float16 half8 __attribute__((ext_vector_type(8)));
typedef float floatx4 __attribute__((ext_vector_type(4)));

#define NB 64
#define NN 2048
#define ND 128
#define NT 1024
#define NSEG 8
#define SEGN 256        // NN / NSEG
#define NTB 4           // t-blocks of 256
#define TBT 256
#define NC 16           // n-rows per chunk
#define NCHUNK 16       // SEGN / NC

#define LP_MAJOR (-1.2039728043259361f)  // log(0.9/3)
#define LP_MINOR (-8.5409097175230770f)  // log(0.1/512)

// ---- prep: W_all (f32, [D][T]) -> t-major f16 hi/lo [t][d] -------------------
__global__ void k_prep(const float* __restrict__ W, const float* __restrict__ Wm,
                       _Float16* __restrict__ Wph, _Float16* __restrict__ Wpl) {
  int idx = blockIdx.x * 256 + threadIdx.x;      // 131072 = 1024*128
  int t = idx >> 7, d = idx & 127;
  float x = (t < 512) ? W[d * 512 + t] : Wm[d * 512 + (t - 512)];
  _Float16 h = (_Float16)x;
  _Float16 l = (_Float16)(x - (float)h);
  Wph[idx] = h;
  Wpl[idx] = l;
}

// ---- shared GEMM chunk: computes S[i=0..15][tloc=0..255] for n0..n0+15 -------
// wave w covers t-range [w*64, w*64+64); B-frags persistent in registers.
#define GEMM_CHUNK()                                                              \
  do {                                                                            \
    floatx4 zf = {0.f, 0.f, 0.f, 0.f};                                            \
    accf[0] = zf; accf[1] = zf; accf[2] = zf; accf[3] = zf;                       \
    _Pragma("unroll")                                                             \
    for (int kk = 0; kk < 4; ++kk) {                                              \
      const float* ap = dbase_p + (size_t)(n0 + l15) * ND + kk * 32 + lhi * 8;    \
      floatx4 a0 = *(const floatx4*)ap;                                           \
      floatx4 a1 = *(const floatx4*)(ap + 4);                                     \
      half8 ah, al;                                                               \
      _Pragma("unroll")                                                           \
      for (int j = 0; j < 4; ++j) {                                               \
        ah[j] = (_Float16)a0[j];                                                  \
        al[j] = (_Float16)(a0[j] - (float)ah[j]);                                 \
        ah[4 + j] = (_Float16)a1[j];                                              \
        al[4 + j] = (_Float16)(a1[j] - (float)ah[4 + j]);                         \
      }                                                                           \
      _Pragma("unroll")                                                           \
      for (int tt = 0; tt < 4; ++tt) {                                            \
        accf[tt] = __builtin_amdgcn_mfma_f32_16x16x32_f16(ah, bh[tt][kk], accf[tt], 0, 0, 0); \
        accf[tt] = __builtin_amdgcn_mfma_f32_16x16x32_f16(ah, bl[tt][kk], accf[tt], 0, 0, 0); \
        accf[tt] = __builtin_amdgcn_mfma_f32_16x16x32_f16(al, bh[tt][kk], accf[tt], 0, 0, 0); \
      }                                                                           \
    }                                                                             \
    __syncthreads(); /* WAR: previous chunk's S reads done */                     \
    _Pragma("unroll")                                                             \
    for (int tt = 0; tt < 4; ++tt)                                                \
      _Pragma("unroll")                                                           \
      for (int r = 0; r < 4; ++r)                                                 \
        S[lhi * 4 + r][w * 64 + tt * 16 + l15] = accf[tt][r];                     \
    __syncthreads();                                                              \
  } while (0)

#define LOAD_BFRAGS()                                                             \
  do {                                                                            \
    int tbb = tb * 256 + w * 64;                                                  \
    _Pragma("unroll")                                                             \
    for (int tt = 0; tt < 4; ++tt)                                                \
      _Pragma("unroll")                                                           \
      for (int kk = 0; kk < 4; ++kk) {                                            \
        int t = tbb + tt * 16 + l15;                                              \
        int off = t * 128 + kk * 32 + lhi * 8;                                    \
        bh[tt][kk] = *(const half8*)(Wph + off);                                  \
        bl[tt][kk] = *(const half8*)(Wpl + off);                                  \
      }                                                                           \
  } while (0)

// ---- pass A: per (b, seg, tblock): sum of diff2 over the segment per t -------
__global__ __launch_bounds__(256, 2)
void k_segsum(const float* __restrict__ data, const float* __restrict__ targets,
              const _Float16* __restrict__ Wph, const _Float16* __restrict__ Wpl,
              float* __restrict__ segsum) {
  int bid = blockIdx.x;
  int tb = bid & 3, seg = (bid >> 2) & 7, b = bid >> 5;
  int tid = threadIdx.x;
  int w = tid >> 6, l = tid & 63;
  int l15 = l & 15, lhi = l >> 4;

  half8 bh[4][4], bl[4][4];
  LOAD_BFRAGS();

  __shared__ float S[NC][TBT + 4];
  floatx4 accf[4];

  const float* dbase_p = data + (size_t)b * NN * ND;
  const float* tbase_p = targets + (size_t)b * NN;

  float acc = 0.f, comp = 0.f;
  int nseg0 = seg * SEGN;
  for (int ch = 0; ch < NCHUNK; ++ch) {
    int n0 = nseg0 + ch * NC;
    GEMM_CHUNK();
#pragma unroll
    for (int i = 0; i < NC; ++i) {
      float s = S[i][tid];
      float tg = tbase_p[n0 + i];
      float df = tg - s;
      float d2 = df * df;
      float y = d2 - comp;            // Kahan
      float t2 = acc + y;
      comp = (t2 - acc) - y;
      acc = t2;
    }
  }
  segsum[((size_t)b * NT + tb * 256 + tid) * NSEG + seg] = acc;
}

// ---- tiny exclusive scan over segments per (b,t) -----------------------------
__global__ void k_scan(const float* __restrict__ segsum, float* __restrict__ carry) {
  int idx = blockIdx.x * 256 + threadIdx.x;   // 65536 = NB*NT
  const float* ss = segsum + (size_t)idx * NSEG;
  float* cr = carry + (size_t)idx * NSEG;
  float a = 0.f;
#pragma unroll
  for (int s = 0; s < NSEG; ++s) { cr[s] = a; a += ss[s]; }
}

// ---- pass C: recompute XW, exclusive prefix, per-wave softmax partials -------
__global__ __launch_bounds__(256, 2)
void k_main(const float* __restrict__ data, const float* __restrict__ targets,
            const _Float16* __restrict__ Wph, const _Float16* __restrict__ Wpl,
            const float* __restrict__ carry, floatx4* __restrict__ part) {
  int bid = blockIdx.x;
  int tb = bid & 3, seg = (bid >> 2) & 7, b = bid >> 5;
  int tid = threadIdx.x;
  int w = tid >> 6, l = tid & 63;
  int l15 = l & 15, lhi = l >> 4;

  half8 bh[4][4], bl[4][4];
  LOAD_BFRAGS();

  __shared__ float S[NC][TBT + 4];
  floatx4 accf[4];

  const float* dbase_p = data + (size_t)b * NN * ND;
  const float* tbase_p = targets + (size_t)b * NN;

  int tg_ = tb * 256 + tid;   // global t this thread owns
  float prior = (tg_ < 512) ? LP_MAJOR : LP_MINOR;
  float acc = carry[((size_t)b * NT + tg_) * NSEG + seg];
  float comp = 0.f;

  int nseg0 = seg * SEGN;
  for (int ch = 0; ch < NCHUNK; ++ch) {
    int n0 = nseg0 + ch * NC;
    GEMM_CHUNK();
    float m_out = 0.f, s1_out = 0.f, s2_out = 0.f;
#pragma unroll
    for (int i = 0; i < NC; ++i) {
      float s = S[i][tid];
      float tg = tbase_p[n0 + i];
      float df = tg - s;
      float d2 = df * df;
      float logp = -0.5f * acc + prior;   // exclusive prefix: acc BEFORE this n
      // wave-wide (64 t's) max
      float m = logp;
#pragma unroll
      for (int off = 1; off < 64; off <<= 1) m = fmaxf(m, __shfl_xor(m, off));
      float e = __expf(logp - m);
      float p1 = e, p2 = e * s;
#pragma unroll
      for (int off = 1; off < 64; off <<= 1) {
        p1 += __shfl_xor(p1, off);
        p2 += __shfl_xor(p2, off);
      }
      if (l == i) { m_out = m; s1_out = p1; s2_out = p2; }
      float y = d2 - comp;                // Kahan update AFTER use
      float t2 = acc + y;
      comp = (t2 - acc) - y;
      acc = t2;
    }
    if (l < NC) {
      floatx4 v;
      v[0] = m_out; v[1] = s1_out; v[2] = s2_out; v[3] = 0.f;
      part[((size_t)b * NN + n0 + l) * 16 + tb * 4 + w] = v;
    }
  }
}

// ---- combine 16 wave-partials per (b,n) --------------------------------------
__global__ void k_combine(const floatx4* __restrict__ part, float* __restrict__ out) {
  int idx = blockIdx.x * 256 + threadIdx.x;   // 131072 = NB*NN
  const floatx4* p = part + (size_t)idx * 16;
  floatx4 v[16];
  float M = -3.4e38f;
#pragma unroll
  for (int j = 0; j < 16; ++j) { v[j] = p[j]; M = fmaxf(M, v[j][0]); }
  float s1 = 0.f, s2 = 0.f;
#pragma unroll
  for (int j = 0; j < 16; ++j) {
    float e = __expf(v[j][0] - M);
    s1 += v[j][1] * e;
    s2 += v[j][2] * e;
  }
  out[idx] = s2 / s1;
}

extern "C" void kernel_launch(void* const* d_in, const int* in_sizes, int n_in,
                              void* d_out, int out_size, void* d_ws, size_t ws_size,
                              hipStream_t stream) {
  const float* data    = (const float*)d_in[0];
  const float* targets = (const float*)d_in[1];
  const float* W       = (const float*)d_in[2];
  const float* Wm      = (const float*)d_in[3];
  float* out = (float*)d_out;

  char* ws = (char*)d_ws;
  _Float16* Wph  = (_Float16*)ws;                                  // 256 KB
  _Float16* Wpl  = (_Float16*)(ws + (256u << 10));                 // 256 KB
  float* segsum  = (float*)(ws + (512u << 10));                    // 2 MB
  float* carry   = (float*)(ws + (512u << 10) + (2u << 20));       // 2 MB
  floatx4* part  = (floatx4*)(ws + (512u << 10) + (4u << 20));     // 32 MB

  k_prep<<<512, 256, 0, stream>>>(W, Wm, Wph, Wpl);
  k_segsum<<<NB * NSEG * NTB, 256, 0, stream>>>(data, targets, Wph, Wpl, segsum);
  k_scan<<<(NB * NT) / 256, 256, 0, stream>>>(segsum, carry);
  k_main<<<NB * NSEG * NTB, 256, 0, stream>>>(data, targets, Wph, Wpl, carry, part);
  k_combine<<<(NB * NN) / 256, 256, 0, stream>>>(part, out);
}

// Round 2
// 429.656 us; speedup vs baseline: 1.7215x; 1.7215x over previous
//
#include <hip/hip_runtime.h>

typedef _Float16 half8 __attribute__((ext_vector_type(8)));
typedef float floatx4 __attribute__((ext_vector_type(4)));

#define NB 64
#define NN 2048
#define ND 128
#define NT 1024
#define NSEG 8
#define SEGN 256        // NN / NSEG
#define NTB 4           // t-blocks of 256
#define TBT 256
#define NC 16           // n-rows per chunk
#define NCHUNK 16       // SEGN / NC

#define LP_MAJOR (-1.2039728043259361f)  // log(0.9/3)
#define LP_MINOR (-8.5409097175230770f)  // log(0.1/512)

// ---- DPP 16-lane rotate all-reduce helpers ----------------------------------
template <int CTRL>
__device__ __forceinline__ float dppmv(float x) {
  int i = __builtin_bit_cast(int, x);
  i = __builtin_amdgcn_update_dpp(i, i, CTRL, 0xF, 0xF, true);
  return __builtin_bit_cast(float, i);
}
__device__ __forceinline__ float rmax16(float x) {
  x = fmaxf(x, dppmv<0x121>(x));  // row_ror:1
  x = fmaxf(x, dppmv<0x122>(x));  // row_ror:2
  x = fmaxf(x, dppmv<0x124>(x));  // row_ror:4
  x = fmaxf(x, dppmv<0x128>(x));  // row_ror:8
  return x;
}
__device__ __forceinline__ float rsum16(float x) {
  x += dppmv<0x121>(x);
  x += dppmv<0x122>(x);
  x += dppmv<0x124>(x);
  x += dppmv<0x128>(x);
  return x;
}

// ---- prep: W_all (f32, [D][T]) -> t-major f16 hi/lo [t][d] -------------------
__global__ void k_prep(const float* __restrict__ W, const float* __restrict__ Wm,
                       _Float16* __restrict__ Wph, _Float16* __restrict__ Wpl) {
  int idx = blockIdx.x * 256 + threadIdx.x;      // 131072 = 1024*128
  int t = idx >> 7, d = idx & 127;
  float x = (t < 512) ? W[d * 512 + t] : Wm[d * 512 + (t - 512)];
  _Float16 h = (_Float16)x;
  _Float16 l = (_Float16)(x - (float)h);
  Wph[idx] = h;
  Wpl[idx] = l;
}

// ---- B-fragment load (persistent in registers) -------------------------------
__device__ __forceinline__ void load_bfrags(const _Float16* __restrict__ Wph,
                                            const _Float16* __restrict__ Wpl,
                                            int tb, int w, int l15, int lhi,
                                            half8 (&bh)[4][4], half8 (&bl)[4][4]) {
  int tbb = tb * 256 + w * 64;
#pragma unroll
  for (int tt = 0; tt < 4; ++tt)
#pragma unroll
    for (int kk = 0; kk < 4; ++kk) {
      int t = tbb + tt * 16 + l15;
      int off = t * 128 + kk * 32 + lhi * 8;
      bh[tt][kk] = *(const half8*)(Wph + off);
      bl[tt][kk] = *(const half8*)(Wpl + off);
    }
}

// ---- GEMM chunk: rows n0..n0+15, f32 A split to f16 hi/lo on the fly ---------
// accf[tt][r] = XW for row (n0 + lhi*4 + r), t = tb*256 + w*64 + tt*16 + l15
__device__ __forceinline__ void gemm_chunk(const float* __restrict__ arow,
                                           int l15, int lhi,
                                           const half8 (&bh)[4][4],
                                           const half8 (&bl)[4][4],
                                           floatx4 (&accf)[4]) {
  floatx4 z = {0.f, 0.f, 0.f, 0.f};
  accf[0] = z; accf[1] = z; accf[2] = z; accf[3] = z;
#pragma unroll
  for (int kk = 0; kk < 4; ++kk) {
    const float* ap = arow + kk * 32;
    floatx4 a0 = *(const floatx4*)ap;
    floatx4 a1 = *(const floatx4*)(ap + 4);
    half8 ah, al;
#pragma unroll
    for (int j = 0; j < 4; ++j) {
      ah[j] = (_Float16)a0[j];
      al[j] = (_Float16)(a0[j] - (float)ah[j]);
      ah[4 + j] = (_Float16)a1[j];
      al[4 + j] = (_Float16)(a1[j] - (float)ah[4 + j]);
    }
#pragma unroll
    for (int tt = 0; tt < 4; ++tt) {
      accf[tt] = __builtin_amdgcn_mfma_f32_16x16x32_f16(ah, bh[tt][kk], accf[tt], 0, 0, 0);
      accf[tt] = __builtin_amdgcn_mfma_f32_16x16x32_f16(ah, bl[tt][kk], accf[tt], 0, 0, 0);
      accf[tt] = __builtin_amdgcn_mfma_f32_16x16x32_f16(al, bh[tt][kk], accf[tt], 0, 0, 0);
    }
  }
}

// ---- pass A: per (b, seg, tblock): sum of diff2 over the segment per t -------
__global__ __launch_bounds__(256, 2)
void k_segsum(const float* __restrict__ data, const float* __restrict__ targets,
              const _Float16* __restrict__ Wph, const _Float16* __restrict__ Wpl,
              float* __restrict__ segsum) {
  int bid = blockIdx.x;
  int tb = bid & 3, seg = (bid >> 2) & 7, b = bid >> 5;
  int tid = threadIdx.x;
  int w = tid >> 6, l = tid & 63;
  int l15 = l & 15, lhi = l >> 4;

  half8 bh[4][4], bl[4][4];
  load_bfrags(Wph, Wpl, tb, w, l15, lhi, bh, bl);

  int nseg0 = seg * SEGN;
  const float* arow = data + (size_t)b * NN * ND + (size_t)(nseg0 + l15) * ND + lhi * 8;
  const float* tgp = targets + (size_t)b * NN + nseg0 + lhi * 4;

  float accs[4] = {0.f, 0.f, 0.f, 0.f};
  floatx4 accf[4];
  for (int ch = 0; ch < NCHUNK; ++ch) {
    gemm_chunk(arow, l15, lhi, bh, bl, accf);
    floatx4 tg = *(const floatx4*)tgp;
#pragma unroll
    for (int tt = 0; tt < 4; ++tt) {
      float d0 = tg[0] - accf[tt][0], d1 = tg[1] - accf[tt][1];
      float d2 = tg[2] - accf[tt][2], d3 = tg[3] - accf[tt][3];
      accs[tt] += d0 * d0 + d1 * d1 + d2 * d2 + d3 * d3;
    }
    arow += NC * ND;
    tgp += NC;
  }
#pragma unroll
  for (int tt = 0; tt < 4; ++tt) {
    float tot = accs[tt];
    tot += __shfl_xor(tot, 16);
    tot += __shfl_xor(tot, 32);
    if (lhi == 0)
      segsum[((size_t)b * NT + tb * 256 + w * 64 + tt * 16 + l15) * NSEG + seg] = tot;
  }
}

// ---- tiny exclusive scan over segments per (b,t) -----------------------------
__global__ void k_scan(const float* __restrict__ segsum, float* __restrict__ carry) {
  int idx = blockIdx.x * 256 + threadIdx.x;   // 65536 = NB*NT
  const float* ss = segsum + (size_t)idx * NSEG;
  float* cr = carry + (size_t)idx * NSEG;
  float a = 0.f;
#pragma unroll
  for (int s = 0; s < NSEG; ++s) { cr[s] = a; a += ss[s]; }
}

// ---- pass C: recompute XW, register-resident prefix + softmax partials -------
__global__ __launch_bounds__(256, 2)
void k_main(const float* __restrict__ data, const float* __restrict__ targets,
            const _Float16* __restrict__ Wph, const _Float16* __restrict__ Wpl,
            const float* __restrict__ carry, floatx4* __restrict__ part) {
  int bid = blockIdx.x;
  int tb = bid & 3, seg = (bid >> 2) & 7, b = bid >> 5;
  int tid = threadIdx.x;
  int w = tid >> 6, l = tid & 63;
  int l15 = l & 15, lhi = l >> 4;

  half8 bh[4][4], bl[4][4];
  load_bfrags(Wph, Wpl, tb, w, l15, lhi, bh, bl);

  float prior = (tb < 2) ? LP_MAJOR : LP_MINOR;   // t<512 <=> tb<2 (block-uniform)

  float acc[4], comp[4] = {0.f, 0.f, 0.f, 0.f};
#pragma unroll
  for (int tt = 0; tt < 4; ++tt)
    acc[tt] = carry[((size_t)b * NT + tb * 256 + w * 64 + tt * 16 + l15) * NSEG + seg];

  int nseg0 = seg * SEGN;
  const float* arow = data + (size_t)b * NN * ND + (size_t)(nseg0 + l15) * ND + lhi * 8;
  const float* tgp = targets + (size_t)b * NN + nseg0 + lhi * 4;

  floatx4 accf[4];
  for (int ch = 0; ch < NCHUNK; ++ch) {
    int n0 = nseg0 + ch * NC;
    gemm_chunk(arow, l15, lhi, bh, bl, accf);
    floatx4 tg = *(const floatx4*)tgp;

    float lp[4][4];   // [tt][r]: log-posterior (pre-softmax) for row lhi*4+r at this lane's t
#pragma unroll
    for (int tt = 0; tt < 4; ++tt) {
      float df0 = tg[0] - accf[tt][0], df1 = tg[1] - accf[tt][1];
      float df2 = tg[2] - accf[tt][2], df3 = tg[3] - accf[tt][3];
      float q0 = df0 * df0, q1 = df1 * df1, q2 = df2 * df2, q3 = df3 * df3;
      float tot = q0 + q1 + q2 + q3;
      // exclusive scan over the 4 lhi groups (rows lhi*4.. come after rows of lower lhi)
      float t16 = __shfl_xor(tot, 16);
      float sum2 = tot + t16;
      float s32 = __shfl_xor(sum2, 32);
      float total = sum2 + s32;
      float excl = ((lhi & 1) ? t16 : 0.f) + ((lhi & 2) ? s32 : 0.f);
      float base = acc[tt] + excl;
      lp[tt][0] = prior - 0.5f * base;
      lp[tt][1] = prior - 0.5f * (base + q0);
      lp[tt][2] = prior - 0.5f * (base + (q0 + q1));
      lp[tt][3] = prior - 0.5f * (base + (q0 + q1 + q2));
      // Kahan-compensated running prefix (chunk-total granularity)
      float y = total - comp[tt];
      float t2 = acc[tt] + y;
      comp[tt] = (t2 - acc[tt]) - y;
      acc[tt] = t2;
    }

    float mv = 0.f, s1v = 0.f, s2v = 0.f;
#pragma unroll
    for (int r = 0; r < 4; ++r) {
      float m = fmaxf(fmaxf(lp[0][r], lp[1][r]), fmaxf(lp[2][r], lp[3][r]));
      m = rmax16(m);                      // all 16 lanes of this lhi group get row max
      float e0 = __expf(lp[0][r] - m), e1 = __expf(lp[1][r] - m);
      float e2 = __expf(lp[2][r] - m), e3 = __expf(lp[3][r] - m);
      float p1 = rsum16(e0 + e1 + e2 + e3);
      float p2 = rsum16(e0 * accf[0][r] + e1 * accf[1][r] +
                        e2 * accf[2][r] + e3 * accf[3][r]);
      if (l15 == r) { mv = m; s1v = p1; s2v = p2; }
    }
    if (l15 < 4) {
      floatx4 v;
      v[0] = mv; v[1] = s1v; v[2] = s2v; v[3] = 0.f;
      part[((size_t)b * NN + n0 + lhi * 4 + l15) * 16 + tb * 4 + w] = v;
    }
    arow += NC * ND;
    tgp += NC;
  }
}

// ---- combine 16 wave-partials per (b,n) --------------------------------------
__global__ void k_combine(const floatx4* __restrict__ part, float* __restrict__ out) {
  int idx = blockIdx.x * 256 + threadIdx.x;   // 131072 = NB*NN
  const floatx4* p = part + (size_t)idx * 16;
  floatx4 v[16];
  float M = -3.4e38f;
#pragma unroll
  for (int j = 0; j < 16; ++j) { v[j] = p[j]; M = fmaxf(M, v[j][0]); }
  float s1 = 0.f, s2 = 0.f;
#pragma unroll
  for (int j = 0; j < 16; ++j) {
    float e = __expf(v[j][0] - M);
    s1 += v[j][1] * e;
    s2 += v[j][2] * e;
  }
  out[idx] = s2 / s1;
}

extern "C" void kernel_launch(void* const* d_in, const int* in_sizes, int n_in,
                              void* d_out, int out_size, void* d_ws, size_t ws_size,
                              hipStream_t stream) {
  const float* data    = (const float*)d_in[0];
  const float* targets = (const float*)d_in[1];
  const float* W       = (const float*)d_in[2];
  const float* Wm      = (const float*)d_in[3];
  float* out = (float*)d_out;

  char* ws = (char*)d_ws;
  _Float16* Wph  = (_Float16*)ws;                                  // 256 KB
  _Float16* Wpl  = (_Float16*)(ws + (256u << 10));                 // 256 KB
  float* segsum  = (float*)(ws + (512u << 10));                    // 2 MB
  float* carry   = (float*)(ws + (512u << 10) + (2u << 20));       // 2 MB
  floatx4* part  = (floatx4*)(ws + (512u << 10) + (4u << 20));     // 32 MB

  k_prep<<<512, 256, 0, stream>>>(W, Wm, Wph, Wpl);
  k_segsum<<<NB * NSEG * NTB, 256, 0, stream>>>(data, targets, Wph, Wpl, segsum);
  k_scan<<<(NB * NT) / 256, 256, 0, stream>>>(segsum, carry);
  k_main<<<NB * NSEG * NTB, 256, 0, stream>>>(data, targets, Wph, Wpl, carry, part);
  k_combine<<<(NB * NN) / 256, 256, 0, stream>>>(part, out);
}

// Round 3
// 335.117 us; speedup vs baseline: 2.2072x; 1.2821x over previous
//
#include <hip/hip_runtime.h>

typedef _Float16 half8 __attribute__((ext_vector_type(8)));
typedef float floatx4 __attribute__((ext_vector_type(4)));

#define NB 64
#define NN 2048
#define ND 128
#define NT 1024
#define NSEG 8
#define SEGN 256        // NN / NSEG
#define NTB 8           // t-blocks of 128 t; each wave owns 32 t
#define NC 16           // n-rows per chunk
#define NCHUNK 16       // SEGN / NC

#define LP_MAJOR (-1.2039728043259361f)  // log(0.9/3)
#define LP_MINOR (-8.5409097175230770f)  // log(0.1/512)

// ---- DPP 16-lane rotate all-reduce helpers ----------------------------------
template <int CTRL>
__device__ __forceinline__ float dppmv(float x) {
  int i = __builtin_bit_cast(int, x);
  i = __builtin_amdgcn_update_dpp(i, i, CTRL, 0xF, 0xF, true);
  return __builtin_bit_cast(float, i);
}
__device__ __forceinline__ float rmax16(float x) {
  x = fmaxf(x, dppmv<0x121>(x));  // row_ror:1
  x = fmaxf(x, dppmv<0x122>(x));  // row_ror:2
  x = fmaxf(x, dppmv<0x124>(x));  // row_ror:4
  x = fmaxf(x, dppmv<0x128>(x));  // row_ror:8
  return x;
}
__device__ __forceinline__ float rsum16(float x) {
  x += dppmv<0x121>(x);
  x += dppmv<0x122>(x);
  x += dppmv<0x124>(x);
  x += dppmv<0x128>(x);
  return x;
}

// ---- prep: W_all (f32, [D][T]) -> t-major f16 hi/lo [t][d] -------------------
__global__ void k_prep(const float* __restrict__ W, const float* __restrict__ Wm,
                       _Float16* __restrict__ Wph, _Float16* __restrict__ Wpl) {
  int idx = blockIdx.x * 256 + threadIdx.x;      // 131072 = 1024*128
  int t = idx >> 7, d = idx & 127;
  float x = (t < 512) ? W[d * 512 + t] : Wm[d * 512 + (t - 512)];
  _Float16 h = (_Float16)x;
  _Float16 l = (_Float16)(x - (float)h);
  Wph[idx] = h;
  Wpl[idx] = l;
}

// ---- prep: data (f32 [B][N][D]) -> fragment-packed f16 hi/lo -----------------
// flat = ((b*128 + ch)*4 + kk)*64 + lane ; element j of lane (lhi,l15) is
// data[b][ch*16 + l15][kk*32 + lhi*8 + j]  (exactly the MFMA A-fragment).
__global__ void k_prep_data(const float* __restrict__ data,
                            _Float16* __restrict__ Ahp, _Float16* __restrict__ Alp) {
  int idx = blockIdx.x * 256 + threadIdx.x;      // 2,097,152 threads
  int l = idx & 63, kk = (idx >> 6) & 3, ch = (idx >> 8) & 127, b = idx >> 15;
  int row = ch * 16 + (l & 15);
  int dcol = kk * 32 + (l >> 4) * 8;
  const float* src = data + ((size_t)b * NN + row) * ND + dcol;
  floatx4 a0 = *(const floatx4*)src;
  floatx4 a1 = *(const floatx4*)(src + 4);
  half8 h, lo;
#pragma unroll
  for (int j = 0; j < 4; ++j) {
    h[j] = (_Float16)a0[j];
    lo[j] = (_Float16)(a0[j] - (float)h[j]);
    h[4 + j] = (_Float16)a1[j];
    lo[4 + j] = (_Float16)(a1[j] - (float)h[4 + j]);
  }
  size_t o = (size_t)idx * 8;
  *(half8*)(Ahp + o) = h;
  *(half8*)(Alp + o) = lo;
}

// ---- B-fragment load (persistent in registers; 64 VGPRs) ---------------------
__device__ __forceinline__ void load_bfrags(const _Float16* __restrict__ Wph,
                                            const _Float16* __restrict__ Wpl,
                                            int tbase, int l15, int lhi,
                                            half8 (&bh)[2][4], half8 (&bl)[2][4]) {
#pragma unroll
  for (int tt = 0; tt < 2; ++tt)
#pragma unroll
    for (int kk = 0; kk < 4; ++kk) {
      int t = tbase + tt * 16 + l15;
      int off = t * 128 + kk * 32 + lhi * 8;
      bh[tt][kk] = *(const half8*)(Wph + off);
      bl[tt][kk] = *(const half8*)(Wpl + off);
    }
}

// ---- GEMM chunk from packed A: accf[tt][r] = XW[n0+lhi*4+r][t(tt,l15)] -------
__device__ __forceinline__ void gemm_chunk(const _Float16* __restrict__ ahp,
                                           const _Float16* __restrict__ alp,
                                           int l,
                                           const half8 (&bh)[2][4],
                                           const half8 (&bl)[2][4],
                                           floatx4 (&accf)[2]) {
  floatx4 z = {0.f, 0.f, 0.f, 0.f};
  accf[0] = z; accf[1] = z;
#pragma unroll
  for (int kk = 0; kk < 4; ++kk) {
    half8 ah = *(const half8*)(ahp + kk * 512 + l * 8);
    half8 al = *(const half8*)(alp + kk * 512 + l * 8);
#pragma unroll
    for (int tt = 0; tt < 2; ++tt) {
      accf[tt] = __builtin_amdgcn_mfma_f32_16x16x32_f16(ah, bh[tt][kk], accf[tt], 0, 0, 0);
      accf[tt] = __builtin_amdgcn_mfma_f32_16x16x32_f16(ah, bl[tt][kk], accf[tt], 0, 0, 0);
      accf[tt] = __builtin_amdgcn_mfma_f32_16x16x32_f16(al, bh[tt][kk], accf[tt], 0, 0, 0);
    }
  }
}

// ---- pass A: per (b, seg, tblock): sum of diff2 over the segment per t -------
__global__ __launch_bounds__(256, 4)
void k_segsum(const _Float16* __restrict__ Ahp, const _Float16* __restrict__ Alp,
              const float* __restrict__ targets,
              const _Float16* __restrict__ Wph, const _Float16* __restrict__ Wpl,
              float* __restrict__ segsum) {
  int bid = blockIdx.x;
  int tb = bid & 7, seg = (bid >> 3) & 7, b = bid >> 6;
  int tid = threadIdx.x;
  int w = tid >> 6, l = tid & 63;
  int l15 = l & 15, lhi = l >> 4;

  half8 bh[2][4], bl[2][4];
  load_bfrags(Wph, Wpl, tb * 128 + w * 32, l15, lhi, bh, bl);

  int nseg0 = seg * SEGN;
  const _Float16* ahp = Ahp + ((size_t)b * 128 + seg * 16) * 2048;
  const _Float16* alp = Alp + ((size_t)b * 128 + seg * 16) * 2048;
  const float* tgp = targets + (size_t)b * NN + nseg0 + lhi * 4;

  float accs[2] = {0.f, 0.f};
  floatx4 accf[2];
  for (int ch = 0; ch < NCHUNK; ++ch) {
    gemm_chunk(ahp, alp, l, bh, bl, accf);
    floatx4 tg = *(const floatx4*)tgp;
#pragma unroll
    for (int tt = 0; tt < 2; ++tt) {
      float d0 = tg[0] - accf[tt][0], d1 = tg[1] - accf[tt][1];
      float d2 = tg[2] - accf[tt][2], d3 = tg[3] - accf[tt][3];
      accs[tt] += d0 * d0 + d1 * d1 + d2 * d2 + d3 * d3;
    }
    ahp += 2048; alp += 2048; tgp += NC;
  }
#pragma unroll
  for (int tt = 0; tt < 2; ++tt) {
    float tot = accs[tt];
    tot += __shfl_xor(tot, 16);
    tot += __shfl_xor(tot, 32);
    if (lhi == 0)
      segsum[((size_t)b * NT + tb * 128 + w * 32 + tt * 16 + l15) * NSEG + seg] = tot;
  }
}

// ---- tiny exclusive scan over segments per (b,t) -----------------------------
__global__ void k_scan(const float* __restrict__ segsum, float* __restrict__ carry) {
  int idx = blockIdx.x * 256 + threadIdx.x;   // 65536 = NB*NT
  const float* ss = segsum + (size_t)idx * NSEG;
  float* cr = carry + (size_t)idx * NSEG;
  float a = 0.f;
#pragma unroll
  for (int s = 0; s < NSEG; ++s) { cr[s] = a; a += ss[s]; }
}

// ---- pass C: recompute XW, register prefix + softmax partials ----------------
__global__ __launch_bounds__(256, 4)
void k_main(const _Float16* __restrict__ Ahp, const _Float16* __restrict__ Alp,
            const float* __restrict__ targets,
            const _Float16* __restrict__ Wph, const _Float16* __restrict__ Wpl,
            const float* __restrict__ carry, floatx4* __restrict__ part) {
  int bid = blockIdx.x;
  int tb = bid & 7, seg = (bid >> 3) & 7, b = bid >> 6;
  int tid = threadIdx.x;
  int w = tid >> 6, l = tid & 63;
  int l15 = l & 15, lhi = l >> 4;

  half8 bh[2][4], bl[2][4];
  load_bfrags(Wph, Wpl, tb * 128 + w * 32, l15, lhi, bh, bl);

  float prior = (tb < 4) ? LP_MAJOR : LP_MINOR;   // t<512 <=> tb<4 (block-uniform)

  float acc[2], comp[2] = {0.f, 0.f};
#pragma unroll
  for (int tt = 0; tt < 2; ++tt)
    acc[tt] = carry[((size_t)b * NT + tb * 128 + w * 32 + tt * 16 + l15) * NSEG + seg];

  int nseg0 = seg * SEGN;
  const _Float16* ahp = Ahp + ((size_t)b * 128 + seg * 16) * 2048;
  const _Float16* alp = Alp + ((size_t)b * 128 + seg * 16) * 2048;
  const float* tgp = targets + (size_t)b * NN + nseg0 + lhi * 4;

  __shared__ float sm[4][16][4];   // [wave][row][{m,s1,s2,pad}]
  floatx4 accf[2];
  for (int ch = 0; ch < NCHUNK; ++ch) {
    int n0 = nseg0 + ch * NC;
    gemm_chunk(ahp, alp, l, bh, bl, accf);
    floatx4 tg = *(const floatx4*)tgp;

    float lp[2][4];
#pragma unroll
    for (int tt = 0; tt < 2; ++tt) {
      float df0 = tg[0] - accf[tt][0], df1 = tg[1] - accf[tt][1];
      float df2 = tg[2] - accf[tt][2], df3 = tg[3] - accf[tt][3];
      float q0 = df0 * df0, q1 = df1 * df1, q2 = df2 * df2, q3 = df3 * df3;
      float tot = q0 + q1 + q2 + q3;
      // exclusive scan over the 4 lhi groups
      float t16 = __shfl_xor(tot, 16);
      float sum2 = tot + t16;
      float s32 = __shfl_xor(sum2, 32);
      float total = sum2 + s32;
      float excl = ((lhi & 1) ? t16 : 0.f) + ((lhi & 2) ? s32 : 0.f);
      float base = acc[tt] + excl;
      lp[tt][0] = prior - 0.5f * base;
      lp[tt][1] = prior - 0.5f * (base + q0);
      lp[tt][2] = prior - 0.5f * (base + (q0 + q1));
      lp[tt][3] = prior - 0.5f * (base + (q0 + q1 + q2));
      // Kahan-compensated running prefix (chunk granularity)
      float y = total - comp[tt];
      float t2 = acc[tt] + y;
      comp[tt] = (t2 - acc[tt]) - y;
      acc[tt] = t2;
    }

    float mv = 0.f, s1v = 0.f, s2v = 0.f;
#pragma unroll
    for (int r = 0; r < 4; ++r) {
      float m = fmaxf(lp[0][r], lp[1][r]);
      m = rmax16(m);                      // max over this wave's 32 t
      float e0 = __expf(lp[0][r] - m), e1 = __expf(lp[1][r] - m);
      float p1 = rsum16(e0 + e1);
      float p2 = rsum16(e0 * accf[0][r] + e1 * accf[1][r]);
      if (l15 == r) { mv = m; s1v = p1; s2v = p2; }
    }

    __syncthreads();                      // WAR: previous chunk's sm reads done
    if (l15 < 4) {
      int row = lhi * 4 + l15;
      sm[w][row][0] = mv; sm[w][row][1] = s1v; sm[w][row][2] = s2v;
    }
    __syncthreads();
    if (tid < 16) {
      float M = fmaxf(fmaxf(sm[0][tid][0], sm[1][tid][0]),
                      fmaxf(sm[2][tid][0], sm[3][tid][0]));
      float S1 = 0.f, S2 = 0.f;
#pragma unroll
      for (int wv = 0; wv < 4; ++wv) {
        float e = __expf(sm[wv][tid][0] - M);
        S1 += sm[wv][tid][1] * e;
        S2 += sm[wv][tid][2] * e;
      }
      floatx4 v;
      v[0] = M; v[1] = S1; v[2] = S2; v[3] = 0.f;
      part[((size_t)b * NN + n0 + tid) * 8 + tb] = v;
    }
    ahp += 2048; alp += 2048; tgp += NC;
  }
}

// ---- combine 8 tb-partials per (b,n) -----------------------------------------
__global__ void k_combine(const floatx4* __restrict__ part, float* __restrict__ out) {
  int idx = blockIdx.x * 256 + threadIdx.x;   // 131072 = NB*NN
  const floatx4* p = part + (size_t)idx * 8;
  floatx4 v[8];
  float M = -3.4e38f;
#pragma unroll
  for (int j = 0; j < 8; ++j) { v[j] = p[j]; M = fmaxf(M, v[j][0]); }
  float s1 = 0.f, s2 = 0.f;
#pragma unroll
  for (int j = 0; j < 8; ++j) {
    float e = __expf(v[j][0] - M);
    s1 += v[j][1] * e;
    s2 += v[j][2] * e;
  }
  out[idx] = s2 / s1;
}

extern "C" void kernel_launch(void* const* d_in, const int* in_sizes, int n_in,
                              void* d_out, int out_size, void* d_ws, size_t ws_size,
                              hipStream_t stream) {
  const float* data    = (const float*)d_in[0];
  const float* targets = (const float*)d_in[1];
  const float* W       = (const float*)d_in[2];
  const float* Wm      = (const float*)d_in[3];
  float* out = (float*)d_out;

  char* ws = (char*)d_ws;
  const size_t MB = 1u << 20;
  _Float16* Wph  = (_Float16*)ws;                          // 256 KB
  _Float16* Wpl  = (_Float16*)(ws + 256 * 1024);           // 256 KB
  _Float16* Ahp  = (_Float16*)(ws + 512 * 1024);           // 32 MB
  _Float16* Alp  = (_Float16*)(ws + 512 * 1024 + 32 * MB); // 32 MB
  float* segsum  = (float*)(ws + 512 * 1024 + 64 * MB);    // 2 MB
  float* carry   = (float*)(ws + 512 * 1024 + 66 * MB);    // 2 MB
  floatx4* part  = (floatx4*)(ws + 512 * 1024 + 68 * MB);  // 16 MB

  k_prep<<<512, 256, 0, stream>>>(W, Wm, Wph, Wpl);
  k_prep_data<<<8192, 256, 0, stream>>>(data, Ahp, Alp);
  k_segsum<<<NB * NSEG * NTB, 256, 0, stream>>>(Ahp, Alp, targets, Wph, Wpl, segsum);
  k_scan<<<(NB * NT) / 256, 256, 0, stream>>>(segsum, carry);
  k_main<<<NB * NSEG * NTB, 256, 0, stream>>>(Ahp, Alp, targets, Wph, Wpl, carry, part);
  k_combine<<<(NB * NN) / 256, 256, 0, stream>>>(part, out);
}

// Round 4
// 309.029 us; speedup vs baseline: 2.3935x; 1.0844x over previous
//
#include <hip/hip_runtime.h>

typedef _Float16 half8 __attribute__((ext_vector_type(8)));
typedef float floatx4 __attribute__((ext_vector_type(4)));

#define NB 64
#define NN 2048
#define ND 128
#define NT 1024
#define NSEG 8
#define SEGN 256        // NN / NSEG
#define NC 16           // n-rows per chunk
#define NCHUNK 16       // SEGN / NC

// exp2-domain constants: alpha^2 = 0.5*log2(e); scaling W,targets by alpha
// makes (alpha*d)^2 sums directly usable as log2 exponents.
#define ALPHA 0.84932184f
#define INV_ALPHA 1.17741002f
#define LP2_MAJOR (-1.7369655941662063f)   // log2(0.9/3)
#define LP2_MINOR (-12.321928094887362f)   // log2(0.1/512)

// bare v_exp_f32 (input already in log2 units, always <= 0 here)
__device__ __forceinline__ float fexp2(float x) {
  float r;
  asm("v_exp_f32 %0, %1" : "=v"(r) : "v"(x));
  return r;
}

// keep-alive pin: forces a loaded value to stay register-resident
#define PIN8(x) asm volatile("" : "+v"(x))

// ---- DPP 16-lane rotate all-reduce helpers ----------------------------------
template <int CTRL>
__device__ __forceinline__ float dppmv(float x) {
  int i = __builtin_bit_cast(int, x);
  i = __builtin_amdgcn_update_dpp(i, i, CTRL, 0xF, 0xF, true);
  return __builtin_bit_cast(float, i);
}
__device__ __forceinline__ float rmax16(float x) {
  x = fmaxf(x, dppmv<0x121>(x));  // row_ror:1
  x = fmaxf(x, dppmv<0x122>(x));  // row_ror:2
  x = fmaxf(x, dppmv<0x124>(x));  // row_ror:4
  x = fmaxf(x, dppmv<0x128>(x));  // row_ror:8
  return x;
}
__device__ __forceinline__ float rsum16(float x) {
  x += dppmv<0x121>(x);
  x += dppmv<0x122>(x);
  x += dppmv<0x124>(x);
  x += dppmv<0x128>(x);
  return x;
}

// ---- prep: W_all (f32, [D][T]) -> alpha-scaled t-major f16 hi/lo [t][d] ------
__global__ void k_prep(const float* __restrict__ W, const float* __restrict__ Wm,
                       _Float16* __restrict__ Wph, _Float16* __restrict__ Wpl) {
  int idx = blockIdx.x * 256 + threadIdx.x;      // 131072 = 1024*128
  int t = idx >> 7, d = idx & 127;
  float x = (t < 512) ? W[d * 512 + t] : Wm[d * 512 + (t - 512)];
  x *= ALPHA;
  _Float16 h = (_Float16)x;
  _Float16 l = (_Float16)(x - (float)h);
  Wph[idx] = h;
  Wpl[idx] = l;
}

// ---- prep: data (f32 [B][N][D]) -> fragment-packed f16 hi/lo -----------------
__global__ void k_prep_data(const float* __restrict__ data,
                            _Float16* __restrict__ Ahp, _Float16* __restrict__ Alp) {
  int idx = blockIdx.x * 256 + threadIdx.x;      // 2,097,152 threads
  int l = idx & 63, kk = (idx >> 6) & 3, ch = (idx >> 8) & 127, b = idx >> 15;
  int row = ch * 16 + (l & 15);
  int dcol = kk * 32 + (l >> 4) * 8;
  const float* src = data + ((size_t)b * NN + row) * ND + dcol;
  floatx4 a0 = *(const floatx4*)src;
  floatx4 a1 = *(const floatx4*)(src + 4);
  half8 h, lo;
#pragma unroll
  for (int j = 0; j < 4; ++j) {
    h[j] = (_Float16)a0[j];
    lo[j] = (_Float16)(a0[j] - (float)h[j]);
    h[4 + j] = (_Float16)a1[j];
    lo[4 + j] = (_Float16)(a1[j] - (float)h[4 + j]);
  }
  size_t o = (size_t)idx * 8;
  *(half8*)(Ahp + o) = h;
  *(half8*)(Alp + o) = lo;
}

// ---- B-fragment load, pinned register-resident (64 VGPRs) --------------------
__device__ __forceinline__ void load_bfrags(const _Float16* __restrict__ Wph,
                                            const _Float16* __restrict__ Wpl,
                                            int tbase, int l15, int lhi,
                                            half8 (&bh)[2][4], half8 (&bl)[2][4]) {
#pragma unroll
  for (int tt = 0; tt < 2; ++tt)
#pragma unroll
    for (int kk = 0; kk < 4; ++kk) {
      int t = tbase + tt * 16 + l15;
      int off = t * 128 + kk * 32 + lhi * 8;
      bh[tt][kk] = *(const half8*)(Wph + off);
      bl[tt][kk] = *(const half8*)(Wpl + off);
    }
#pragma unroll
  for (int tt = 0; tt < 2; ++tt)
#pragma unroll
    for (int kk = 0; kk < 4; ++kk) { PIN8(bh[tt][kk]); PIN8(bl[tt][kk]); }
}

// ---- GEMM chunk from packed A: accf[tt][r] = alpha*XW[n0+lhi*4+r][t] ---------
__device__ __forceinline__ void gemm_chunk(const _Float16* __restrict__ ahp,
                                           const _Float16* __restrict__ alp,
                                           int l,
                                           const half8 (&bh)[2][4],
                                           const half8 (&bl)[2][4],
                                           floatx4 (&accf)[2]) {
  floatx4 z = {0.f, 0.f, 0.f, 0.f};
  accf[0] = z; accf[1] = z;
#pragma unroll
  for (int kk = 0; kk < 4; ++kk) {
    half8 ah = *(const half8*)(ahp + kk * 512 + l * 8);
    half8 al = *(const half8*)(alp + kk * 512 + l * 8);
#pragma unroll
    for (int tt = 0; tt < 2; ++tt) {
      accf[tt] = __builtin_amdgcn_mfma_f32_16x16x32_f16(ah, bh[tt][kk], accf[tt], 0, 0, 0);
      accf[tt] = __builtin_amdgcn_mfma_f32_16x16x32_f16(ah, bl[tt][kk], accf[tt], 0, 0, 0);
      accf[tt] = __builtin_amdgcn_mfma_f32_16x16x32_f16(al, bh[tt][kk], accf[tt], 0, 0, 0);
    }
  }
}

// ---- pass A: per (b, seg, tblock): sum of (alpha*diff)^2 over segment per t --
__global__ __launch_bounds__(256, 4)
void k_segsum(const _Float16* __restrict__ Ahp, const _Float16* __restrict__ Alp,
              const float* __restrict__ targets,
              const _Float16* __restrict__ Wph, const _Float16* __restrict__ Wpl,
              float* __restrict__ segsum) {
  int bid = blockIdx.x;
  int seg = bid & 7, tb = (bid >> 3) & 7, b = bid >> 6;   // seg -> XCD; tb-partners co-XCD
  int tid = threadIdx.x;
  int w = tid >> 6, l = tid & 63;
  int l15 = l & 15, lhi = l >> 4;

  half8 bh[2][4], bl[2][4];
  load_bfrags(Wph, Wpl, tb * 128 + w * 32, l15, lhi, bh, bl);

  int nseg0 = seg * SEGN;
  const _Float16* ahp = Ahp + ((size_t)b * 128 + seg * 16) * 2048;
  const _Float16* alp = Alp + ((size_t)b * 128 + seg * 16) * 2048;
  const float* tgp = targets + (size_t)b * NN + nseg0 + lhi * 4;

  float accs[2] = {0.f, 0.f};
  floatx4 accf[2];
  for (int ch = 0; ch < NCHUNK; ++ch) {
    gemm_chunk(ahp, alp, l, bh, bl, accf);
    floatx4 tg = *(const floatx4*)tgp * ALPHA;
#pragma unroll
    for (int tt = 0; tt < 2; ++tt) {
      float d0 = tg[0] - accf[tt][0], d1 = tg[1] - accf[tt][1];
      float d2 = tg[2] - accf[tt][2], d3 = tg[3] - accf[tt][3];
      accs[tt] += d0 * d0 + d1 * d1 + d2 * d2 + d3 * d3;
    }
    ahp += 2048; alp += 2048; tgp += NC;
  }
#pragma unroll
  for (int tt = 0; tt < 2; ++tt) {
    float tot = accs[tt];
    tot += __shfl_xor(tot, 16);
    tot += __shfl_xor(tot, 32);
    if (lhi == 0)
      segsum[((size_t)b * NT + tb * 128 + w * 32 + tt * 16 + l15) * NSEG + seg] = tot;
  }
}

// ---- tiny exclusive scan over segments per (b,t) -----------------------------
__global__ void k_scan(const float* __restrict__ segsum, float* __restrict__ carry) {
  int idx = blockIdx.x * 256 + threadIdx.x;   // 65536 = NB*NT
  const float* ss = segsum + (size_t)idx * NSEG;
  float* cr = carry + (size_t)idx * NSEG;
  float a = 0.f;
#pragma unroll
  for (int s = 0; s < NSEG; ++s) { cr[s] = a; a += ss[s]; }
}

// ---- pass C: recompute XW, register prefix + softmax partials ----------------
__global__ __launch_bounds__(256, 4)
void k_main(const _Float16* __restrict__ Ahp, const _Float16* __restrict__ Alp,
            const float* __restrict__ targets,
            const _Float16* __restrict__ Wph, const _Float16* __restrict__ Wpl,
            const float* __restrict__ carry, floatx4* __restrict__ part) {
  int bid = blockIdx.x;
  int seg = bid & 7, tb = (bid >> 3) & 7, b = bid >> 6;
  int tid = threadIdx.x;
  int w = tid >> 6, l = tid & 63;
  int l15 = l & 15, lhi = l >> 4;

  half8 bh[2][4], bl[2][4];
  load_bfrags(Wph, Wpl, tb * 128 + w * 32, l15, lhi, bh, bl);

  float prior2 = (tb < 4) ? LP2_MAJOR : LP2_MINOR;   // t<512 <=> tb<4

  float acc[2], comp[2] = {0.f, 0.f};
#pragma unroll
  for (int tt = 0; tt < 2; ++tt)
    acc[tt] = carry[((size_t)b * NT + tb * 128 + w * 32 + tt * 16 + l15) * NSEG + seg];

  int nseg0 = seg * SEGN;
  const _Float16* ahp = Ahp + ((size_t)b * 128 + seg * 16) * 2048;
  const _Float16* alp = Alp + ((size_t)b * 128 + seg * 16) * 2048;
  const float* tgp = targets + (size_t)b * NN + nseg0 + lhi * 4;
  size_t pbase = ((size_t)b * NN + nseg0) * 8 + tb;

  __shared__ float sm[4][4][16][5];   // [wave][chunk%4][row][{m,s1,s2,pad,pad}]
  floatx4 accf[2];
  for (int ch = 0; ch < NCHUNK; ++ch) {
    gemm_chunk(ahp, alp, l, bh, bl, accf);
    floatx4 tg = *(const floatx4*)tgp * ALPHA;

    float lp[2][4];   // log2-domain posteriors
#pragma unroll
    for (int tt = 0; tt < 2; ++tt) {
      float df0 = tg[0] - accf[tt][0], df1 = tg[1] - accf[tt][1];
      float df2 = tg[2] - accf[tt][2], df3 = tg[3] - accf[tt][3];
      float q0 = df0 * df0, q1 = df1 * df1, q2 = df2 * df2, q3 = df3 * df3;
      float tot = q0 + q1 + q2 + q3;
      // exclusive scan over the 4 lhi groups
      float t16 = __shfl_xor(tot, 16);
      float sum2 = tot + t16;
      float s32 = __shfl_xor(sum2, 32);
      float total = sum2 + s32;
      float excl = ((lhi & 1) ? t16 : 0.f) + ((lhi & 2) ? s32 : 0.f);
      float base = acc[tt] + excl;
      lp[tt][0] = prior2 - base;
      lp[tt][1] = prior2 - (base + q0);
      lp[tt][2] = prior2 - (base + (q0 + q1));
      lp[tt][3] = prior2 - (base + (q0 + q1 + q2));
      // Kahan-compensated running prefix (chunk granularity)
      float y = total - comp[tt];
      float t2 = acc[tt] + y;
      comp[tt] = (t2 - acc[tt]) - y;
      acc[tt] = t2;
    }

    float mv = 0.f, s1v = 0.f, s2v = 0.f;
#pragma unroll
    for (int r = 0; r < 4; ++r) {
      float m = rmax16(fmaxf(lp[0][r], lp[1][r]));   // max over this wave's 32 t
      float e0 = fexp2(lp[0][r] - m), e1 = fexp2(lp[1][r] - m);
      float p1 = rsum16(e0 + e1);
      float p2 = rsum16(e0 * accf[0][r] + e1 * accf[1][r]);
      bool sel = (l15 == r);
      mv = sel ? m : mv; s1v = sel ? p1 : s1v; s2v = sel ? p2 : s2v;
    }
    if (l15 < 4) {
      int row = lhi * 4 + l15;
      sm[w][ch & 3][row][0] = mv;
      sm[w][ch & 3][row][1] = s1v;
      sm[w][ch & 3][row][2] = s2v;
    }
    if ((ch & 3) == 3) {               // merge 4 chunks' partials across waves
      __syncthreads();
      if (tid < 64) {
        int c4 = tid >> 4, row = tid & 15;
        float m0 = sm[0][c4][row][0], m1 = sm[1][c4][row][0];
        float m2 = sm[2][c4][row][0], m3 = sm[3][c4][row][0];
        float M = fmaxf(fmaxf(m0, m1), fmaxf(m2, m3));
        float e0 = fexp2(m0 - M), e1 = fexp2(m1 - M);
        float e2 = fexp2(m2 - M), e3 = fexp2(m3 - M);
        float S1 = sm[0][c4][row][1] * e0 + sm[1][c4][row][1] * e1 +
                   sm[2][c4][row][1] * e2 + sm[3][c4][row][1] * e3;
        float S2 = sm[0][c4][row][2] * e0 + sm[1][c4][row][2] * e1 +
                   sm[2][c4][row][2] * e2 + sm[3][c4][row][2] * e3;
        floatx4 v;
        v[0] = M; v[1] = S1; v[2] = S2; v[3] = 0.f;
        part[pbase + (size_t)((ch - 3 + c4) * 16 + row) * 8] = v;
      }
      __syncthreads();
    }
    ahp += 2048; alp += 2048; tgp += NC;
  }
}

// ---- combine 8 tb-partials per (b,n) -----------------------------------------
__global__ void k_combine(const floatx4* __restrict__ part, float* __restrict__ out) {
  int idx = blockIdx.x * 256 + threadIdx.x;   // 131072 = NB*NN
  const floatx4* p = part + (size_t)idx * 8;
  floatx4 v[8];
  float M = -3.4e38f;
#pragma unroll
  for (int j = 0; j < 8; ++j) { v[j] = p[j]; M = fmaxf(M, v[j][0]); }
  float s1 = 0.f, s2 = 0.f;
#pragma unroll
  for (int j = 0; j < 8; ++j) {
    float e = fexp2(v[j][0] - M);
    s1 += v[j][1] * e;
    s2 += v[j][2] * e;
  }
  out[idx] = s2 / s1 * INV_ALPHA;   // undo alpha scale on XW values
}

extern "C" void kernel_launch(void* const* d_in, const int* in_sizes, int n_in,
                              void* d_out, int out_size, void* d_ws, size_t ws_size,
                              hipStream_t stream) {
  const float* data    = (const float*)d_in[0];
  const float* targets = (const float*)d_in[1];
  const float* W       = (const float*)d_in[2];
  const float* Wm      = (const float*)d_in[3];
  float* out = (float*)d_out;

  char* ws = (char*)d_ws;
  const size_t MB = 1u << 20;
  _Float16* Wph  = (_Float16*)ws;                          // 256 KB
  _Float16* Wpl  = (_Float16*)(ws + 256 * 1024);           // 256 KB
  _Float16* Ahp  = (_Float16*)(ws + 512 * 1024);           // 32 MB
  _Float16* Alp  = (_Float16*)(ws + 512 * 1024 + 32 * MB); // 32 MB
  float* segsum  = (float*)(ws + 512 * 1024 + 64 * MB);    // 2 MB
  float* carry   = (float*)(ws + 512 * 1024 + 66 * MB);    // 2 MB
  floatx4* part  = (floatx4*)(ws + 512 * 1024 + 68 * MB);  // 16 MB

  k_prep<<<512, 256, 0, stream>>>(W, Wm, Wph, Wpl);
  k_prep_data<<<8192, 256, 0, stream>>>(data, Ahp, Alp);
  k_segsum<<<NB * NSEG * 8, 256, 0, stream>>>(Ahp, Alp, targets, Wph, Wpl, segsum);
  k_scan<<<(NB * NT) / 256, 256, 0, stream>>>(segsum, carry);
  k_main<<<NB * NSEG * 8, 256, 0, stream>>>(Ahp, Alp, targets, Wph, Wpl, carry, part);
  k_combine<<<(NB * NN) / 256, 256, 0, stream>>>(part, out);
}